// Round 10
// baseline (1267.971 us; speedup 1.0000x reference)
//
#include <hip/hip_runtime.h>

#define NN 100000
#define EE 1600000
#define FF 128
#define LL 4
#define GG 512
#define OUTC 10
#define EPSF 1e-5f
#define NSCB ((NN + 255) / 256)   // 391 scan blocks

typedef __attribute__((ext_vector_type(8))) short short8;
typedef __attribute__((ext_vector_type(4))) float f32x4;

__device__ inline unsigned bf16rne(float f) {
  unsigned u = __float_as_uint(f);
  return (u + 0x7fffu + ((u >> 16) & 1u)) >> 16;
}
__device__ inline unsigned packbf(float lo, float hi) {
  return bf16rne(lo) | (bf16rne(hi) << 16);
}
__device__ inline float bflo(unsigned u) { return __uint_as_float(u << 16); }
__device__ inline float bfhi(unsigned u) { return __uint_as_float(u & 0xffff0000u); }

// ---------- graph setup ----------

__global__ __launch_bounds__(256) void k_deg(const int* __restrict__ col, int* __restrict__ deg) {
  int e = blockIdx.x * 256 + threadIdx.x;
  if (e < EE) atomicAdd(&deg[col[e]], 1);
}

__global__ __launch_bounds__(256) void k_dinv(const int* __restrict__ deg, float* __restrict__ dinv) {
  int n = blockIdx.x * 256 + threadIdx.x;
  if (n < NN) {
    int d = deg[n];
    dinv[n] = d > 0 ? rsqrtf((float)d) : 0.0f;
  }
}

// per-block degree sums (391 blocks x 256)
__global__ __launch_bounds__(256) void k_bsum(const int* __restrict__ deg, int* __restrict__ bsum) {
  int i = blockIdx.x * 256 + threadIdx.x;
  int v = (i < NN) ? deg[i] : 0;
#pragma unroll
  for (int off = 32; off > 0; off >>= 1) v += __shfl_down(v, off, 64);
  __shared__ int ws[4];
  if ((threadIdx.x & 63) == 0) ws[threadIdx.x >> 6] = v;
  __syncthreads();
  if (threadIdx.x == 0) bsum[blockIdx.x] = ws[0] + ws[1] + ws[2] + ws[3];
}

// each block: scan all block sums in LDS (redundant), local scan of its 256 degs,
// write exclusive rowptr. rowptr[NN] = EE (constant).
__global__ __launch_bounds__(256) void k_rowptr(const int* __restrict__ deg,
                                                const int* __restrict__ bsum,
                                                int* __restrict__ rowptr) {
  __shared__ int sb[512];
  __shared__ int sd[256];
  const int t = threadIdx.x;
  sb[t]       = (t < NSCB) ? bsum[t] : 0;
  sb[t + 256] = (t + 256 < NSCB) ? bsum[t + 256] : 0;
  __syncthreads();
#pragma unroll
  for (int off = 1; off < 512; off <<= 1) {
    int v0 = (t >= off) ? sb[t - off] : 0;
    int v1 = sb[t + 256 - off];
    __syncthreads();
    sb[t] += v0;
    sb[t + 256] += v1;
    __syncthreads();
  }
  const int bpre = (blockIdx.x == 0) ? 0 : sb[blockIdx.x - 1];
  const int i = blockIdx.x * 256 + t;
  const int d = (i < NN) ? deg[i] : 0;
  sd[t] = d;
  __syncthreads();
#pragma unroll
  for (int off = 1; off < 256; off <<= 1) {
    int v = (t >= off) ? sd[t - off] : 0;
    __syncthreads();
    sd[t] += v;
    __syncthreads();
  }
  if (i < NN) rowptr[i] = bpre + sd[t] - d;
  if (blockIdx.x == 0 && t == 0) rowptr[NN] = EE;
}

// build CSR: one interleaved (src, weight) int2 store per edge
__global__ __launch_bounds__(256) void k_fill(const int* __restrict__ ei,
                                              const int* __restrict__ rowptr,
                                              int* __restrict__ cnt,
                                              const float* __restrict__ dinv,
                                              int2* __restrict__ ecw) {
  int e = blockIdx.x * 256 + threadIdx.x;
  if (e >= EE) return;
  int r = ei[e];
  int cl = ei[EE + e];
  int slot = rowptr[cl] + atomicAdd(&cnt[cl], 1);
  ecw[slot] = make_int2(r, __float_as_int(dinv[r] * dinv[cl]));
}

// batch is sorted: gstart[g] = first node of graph g; gstart[GG] = NN
__global__ __launch_bounds__(256) void k_bounds(const int* __restrict__ batch, int* __restrict__ gstart) {
  int n = blockIdx.x * 256 + threadIdx.x;
  if (n >= NN) return;
  int b = batch[n];
  if (n == 0) {
    for (int g = 0; g <= b; ++g) gstart[g] = 0;
  } else {
    int bp = batch[n - 1];
    for (int g = bp + 1; g <= b; ++g) gstart[g] = n;
  }
  if (n == NN - 1) {
    for (int g = b + 1; g <= GG; ++g) gstart[g] = NN;
  }
}

// ---------- bf16 conversions ----------

// x[N,128] fp32 -> Ab packed bf16 pairs
__global__ __launch_bounds__(256) void k_cvt(const float* __restrict__ x, unsigned* __restrict__ Ab) {
  int i = blockIdx.x * 256 + threadIdx.x;
  if (i < NN * 64) {
    float2 v = *(const float2*)(x + (size_t)i * 2);
    Ab[i] = packbf(v.x, v.y);
  }
}

// identity affine table for layer 0
__global__ __launch_bounds__(128) void k_id(float* __restrict__ idt) {
  idt[threadIdx.x] = 1.0f;
  idt[128 + threadIdx.x] = 0.0f;
}

// W[L,128,128] fp32 -> per-layer MFMA B-fragments, hi/lo bf16 split.
__global__ __launch_bounds__(256) void k_wcvt(const float* __restrict__ Ws, uint4* __restrict__ Wf) {
  int tid = blockIdx.x * 256 + threadIdx.x;   // 0..16383
  int t = tid >> 12;
  int r = tid & 4095;
  int lane = r & 63;
  int which = (r >> 6) & 1;
  int ct = (r >> 7) & 7;
  int kc = r >> 10;
  int n = ct * 16 + (lane & 15);
  int k0 = kc * 32 + (lane >> 4) * 8;
  const float* W = Ws + t * 16384;
  unsigned h[8];
#pragma unroll
  for (int j = 0; j < 8; ++j) {
    float w = W[(k0 + j) * 128 + n];
    unsigned hb = bf16rne(w);
    if (which == 0) {
      h[j] = hb;
    } else {
      float hf = __uint_as_float(hb << 16);
      h[j] = bf16rne(w - hf);
    }
  }
  uint4 o;
  o.x = h[0] | (h[1] << 16);
  o.y = h[2] | (h[3] << 16);
  o.z = h[4] | (h[5] << 16);
  o.w = h[6] | (h[7] << 16);
  Wf[tid] = o;
}

// ---------- per-layer GEMM via MFMA with fused input BN affine ----------
// Bb (slice-major: [8 slices][NN][8 uints]) = (aff_sc * Hb + aff_sh) @ (Whi+Wlo)
__global__ __launch_bounds__(256) void k_mm(const unsigned* __restrict__ Hb,
                                            const float* __restrict__ aff,   // [256] sc|sh
                                            const uint4* __restrict__ Wf,
                                            unsigned* __restrict__ Bb) {
  const int lane = threadIdx.x & 63;
  const int w = threadIdx.x >> 6;
  const int quad = lane >> 4;
  const int m = lane & 15;
  const int rowbase = blockIdx.x * 64 + w * 16;
  const int arow = min(rowbase + m, NN - 1);
  const uint4* A4 = (const uint4*)Hb;
  f32x4 acc[8];
#pragma unroll
  for (int ct = 0; ct < 8; ++ct) acc[ct] = (f32x4){0.f, 0.f, 0.f, 0.f};
#pragma unroll
  for (int kc = 0; kc < 4; ++kc) {
    uint4 av = A4[arow * 16 + kc * 4 + quad];
    const int cb = kc * 32 + quad * 8;
    float4 sc0 = *(const float4*)(aff + cb);
    float4 sc1 = *(const float4*)(aff + cb + 4);
    float4 sh0 = *(const float4*)(aff + 128 + cb);
    float4 sh1 = *(const float4*)(aff + 128 + cb + 4);
    uint4 hv;
    hv.x = packbf(fmaf(bflo(av.x), sc0.x, sh0.x), fmaf(bfhi(av.x), sc0.y, sh0.y));
    hv.y = packbf(fmaf(bflo(av.y), sc0.z, sh0.z), fmaf(bfhi(av.y), sc0.w, sh0.w));
    hv.z = packbf(fmaf(bflo(av.z), sc1.x, sh1.x), fmaf(bfhi(av.z), sc1.y, sh1.y));
    hv.w = packbf(fmaf(bflo(av.w), sc1.z, sh1.z), fmaf(bfhi(av.w), sc1.w, sh1.w));
    short8 af = *(short8*)&hv;
#pragma unroll
    for (int ct = 0; ct < 8; ++ct) {
      uint4 bh = Wf[((kc * 8 + ct) * 2 + 0) * 64 + lane];
      uint4 bl = Wf[((kc * 8 + ct) * 2 + 1) * 64 + lane];
      acc[ct] = __builtin_amdgcn_mfma_f32_16x16x32_bf16(af, *(short8*)&bh, acc[ct], 0, 0, 0);
      acc[ct] = __builtin_amdgcn_mfma_f32_16x16x32_bf16(af, *(short8*)&bl, acc[ct], 0, 0, 0);
    }
  }
#pragma unroll
  for (int ct = 0; ct < 8; ++ct) {
#pragma unroll
    for (int r = 0; r < 4; ++r) {
      float v = acc[ct][r];
      float vo = __shfl_xor(v, 1);
      int row = rowbase + quad * 4 + r;
      if ((lane & 1) == 0 && row < NN) {
        Bb[(size_t)ct * NN * 8 + row * 8 + (m >> 1)] = packbf(v, vo);
      }
    }
  }
}

// ---------- aggregation, XCD-sliced, shuffle-free edge loop ----------
// slice s = blockIdx%8 (round-robin workgroup->XCD => each XCD re-reads only its
// 3.2 MB Bb slice, L2-resident). Wave lane = (edge e=lane>>3, uint j=lane&7);
// the 8 lanes of an e-group load the SAME ecw entry directly (HW broadcast,
// chunk's 512 B is L1-resident across its 8 group-reads) -- no ds_bpermute.
// Two acc pairs (group parity) for ILP; per-node butterfly reduce over e.
__global__ __launch_bounds__(256) void k_agg(const unsigned* __restrict__ Bb,
                                             const int* __restrict__ rowptr,
                                             const int2* __restrict__ ecw,
                                             const float* __restrict__ bias,
                                             unsigned* __restrict__ Ar,
                                             float* __restrict__ bnbuf) {
  const int lane = threadIdx.x & 63;
  const int wave = threadIdx.x >> 6;
  const int e = lane >> 3;
  const int j = lane & 7;
  const int s = blockIdx.x & 7;
  const int rb = blockIdx.x >> 3;
  const int wrank = rb * 4 + wave;          // 0..1023 per slice
  const unsigned* Bs = Bb + (size_t)s * NN * 8;
  const float2 bv = ((const float2*)bias)[s * 8 + j];
  float s0 = 0.f, s1 = 0.f, q0 = 0.f, q1 = 0.f;
  for (int n = wrank; n < NN; n += 1024) {
    const int beg = rowptr[n];
    const int end = rowptr[n + 1];
    float a0 = 0.f, a1 = 0.f, b0 = 0.f, b1 = 0.f;
    for (int base = beg; base < end; base += 64) {
#pragma unroll
      for (int g = 0; g < 8; ++g) {
        if (base + g * 8 < end) {   // wave-uniform group guard
          const int ee = base + g * 8 + e;
          const int2 p = ecw[min(ee, end - 1)];
          const float w = (ee < end) ? __int_as_float(p.y) : 0.f;
          const unsigned uu = Bs[(unsigned)p.x * 8u + (unsigned)j];
          if (g & 1) { b0 = fmaf(w, bflo(uu), b0); b1 = fmaf(w, bfhi(uu), b1); }
          else       { a0 = fmaf(w, bflo(uu), a0); a1 = fmaf(w, bfhi(uu), a1); }
        }
      }
    }
    a0 += b0; a1 += b1;
    a0 += __shfl_xor(a0, 8);  a1 += __shfl_xor(a1, 8);
    a0 += __shfl_xor(a0, 16); a1 += __shfl_xor(a1, 16);
    a0 += __shfl_xor(a0, 32); a1 += __shfl_xor(a1, 32);
    float rx = fmaxf(a0 + bv.x, 0.f);
    float ry = fmaxf(a1 + bv.y, 0.f);
    if (e == 0) {
      Ar[(size_t)n * 64 + s * 8 + j] = packbf(rx, ry);
      s0 += rx; s1 += ry;
      q0 = fmaf(rx, rx, q0); q1 = fmaf(ry, ry, q1);
    }
  }
  __shared__ float sred[4][32];
  if (e == 0) {
    sred[wave][j * 4 + 0] = s0;
    sred[wave][j * 4 + 1] = s1;
    sred[wave][j * 4 + 2] = q0;
    sred[wave][j * 4 + 3] = q1;
  }
  __syncthreads();
  const int t = threadIdx.x;
  if (t < 32) {
    float tot = (sred[0][t] + sred[1][t]) + (sred[2][t] + sred[3][t]);
    const int jj = t >> 2;
    const int comp = t & 3;
    const int c = s * 16 + 2 * jj + (comp & 1);
    atomicAdd(&bnbuf[(comp >> 1) * 128 + c], tot);
  }
}

__global__ __launch_bounds__(128) void k_bnfin(const float* __restrict__ bnbuf,
                                               const float* __restrict__ gamma,
                                               const float* __restrict__ beta,
                                               float* __restrict__ bnsc) {
  const int c = threadIdx.x;
  float mu = bnbuf[c] * (1.0f / NN);
  float var = bnbuf[128 + c] * (1.0f / NN) - mu * mu;
  float inv = rsqrtf(var + EPSF);
  float sc = gamma[c] * inv;
  bnsc[c] = sc;
  bnsc[128 + c] = beta[c] - mu * sc;
}

// per-graph raw pooled sums of relu output (sorted ranges, coarse atomics)
__global__ __launch_bounds__(128) void k_gsum(const unsigned* __restrict__ Ar,
                                              const int* __restrict__ gstart,
                                              float* __restrict__ praw) {
  const int g = blockIdx.x >> 3;
  const int sub = blockIdx.x & 7;
  const int st = gstart[g];
  const int en = gstart[g + 1];
  const int cnt = en - st;
  if (cnt <= 0) return;
  const int per = (cnt + 7) >> 3;
  const int ns = st + sub * per;
  const int ne = min(ns + per, en);
  if (ns >= ne) return;
  const int cp = threadIdx.x & 63;
  const int half = threadIdx.x >> 6;
  float accx = 0.f, accy = 0.f;
  for (int n = ns + half; n < ne; n += 2) {
    unsigned u = Ar[(size_t)n * 64 + cp];
    accx += bflo(u);
    accy += bfhi(u);
  }
  atomicAdd(&praw[(size_t)g * 128 + 2 * cp], accx);
  atomicAdd(&praw[(size_t)g * 128 + 2 * cp + 1], accy);
}

// pooled[g, t*128+c] = sc[c]*S_g[c] + sh[c]*cnt_g (linearized BN over per-graph sums)
__global__ __launch_bounds__(128) void k_pool(const float* __restrict__ praw,
                                              const float* __restrict__ bnsc,
                                              const int* __restrict__ gstart,
                                              float* __restrict__ pooledt) {
  const int g = blockIdx.x;
  const int c = threadIdx.x;
  const float cntf = (float)(gstart[g + 1] - gstart[g]);
  pooledt[(size_t)g * 512 + c] = fmaf(bnsc[c], praw[(size_t)g * 128 + c], bnsc[128 + c] * cntf);
}

// ---------- head ----------

__global__ __launch_bounds__(128) void k_z1(const float* __restrict__ pooled,
                                            const float* __restrict__ W1,
                                            const float* __restrict__ b1,
                                            float* __restrict__ z1) {
  __shared__ float sp[512];
  const int g = blockIdx.x;
  for (int i = threadIdx.x; i < 512; i += 128) sp[i] = pooled[(size_t)g * 512 + i];
  __syncthreads();
  const int c = threadIdx.x;
  float acc = b1[c];
  for (int j = 0; j < 512; ++j) acc = fmaf(sp[j], W1[j * 128 + c], acc);
  z1[(size_t)g * 128 + c] = acc;
}

__global__ __launch_bounds__(128) void k_zstat(const float* __restrict__ z1,
                                               const float* __restrict__ g1,
                                               const float* __restrict__ bt1,
                                               float* __restrict__ zsc) {
  const int c = threadIdx.x;
  float s = 0.f, q = 0.f;
  for (int g = 0; g < GG; ++g) {
    float v = z1[g * 128 + c];
    s += v;
    q = fmaf(v, v, q);
  }
  float mu = s * (1.0f / GG);
  float var = q * (1.0f / GG) - mu * mu;
  float inv = rsqrtf(var + EPSF);
  float sc = g1[c] * inv;
  zsc[c] = sc;
  zsc[128 + c] = bt1[c] - mu * sc;
}

__global__ __launch_bounds__(128) void k_out(const float* __restrict__ z1,
                                             const float* __restrict__ zsc,
                                             const float* __restrict__ W2,
                                             const float* __restrict__ b2,
                                             float* __restrict__ out) {
  __shared__ float zr[128];
  const int g = blockIdx.x;
  const int c = threadIdx.x;
  zr[c] = fmaxf(fmaf(z1[(size_t)g * 128 + c], zsc[c], zsc[128 + c]), 0.f);
  __syncthreads();
  if (c < OUTC) {
    float acc = b2[c];
    for (int k = 0; k < 128; ++k) acc = fmaf(zr[k], W2[k * OUTC + c], acc);
    out[(size_t)g * OUTC + c] = acc;
  }
}

// ---------- launch ----------

extern "C" void kernel_launch(void* const* d_in, const int* in_sizes, int n_in,
                              void* d_out, int out_size, void* d_ws, size_t ws_size,
                              hipStream_t stream) {
  const float* x      = (const float*)d_in[0];
  const int*   ei     = (const int*)d_in[1];
  const int*   batch  = (const int*)d_in[2];
  const float* Ws     = (const float*)d_in[3];
  const float* bs     = (const float*)d_in[4];
  const float* gammas = (const float*)d_in[5];
  const float* betas  = (const float*)d_in[6];
  const float* W1     = (const float*)d_in[7];
  const float* b1     = (const float*)d_in[8];
  const float* g1     = (const float*)d_in[9];
  const float* bt1    = (const float*)d_in[10];
  const float* W2     = (const float*)d_in[11];
  const float* b2     = (const float*)d_in[12];
  float* out = (float*)d_out;

  char* ws = (char*)d_ws;
  size_t off = 0;
  auto alloc = [&](size_t bytes) -> void* {
    void* p = ws + off;
    off = (off + bytes + 255) & ~(size_t)255;
    return p;
  };
  // zero-initialized region (single memset)
  int*   deg    = (int*)alloc((size_t)NN * 4);
  int*   cnt    = (int*)alloc((size_t)NN * 4);
  float* bnbuf  = (float*)alloc((size_t)LL * 256 * 4);
  float* praw   = (float*)alloc((size_t)LL * GG * 128 * 4);
  size_t zero_bytes = off;
  // rest
  float* pooled    = (float*)alloc((size_t)GG * 512 * 4);
  unsigned* Ar     = (unsigned*)alloc((size_t)NN * 64 * 4); // packed bf16 relu output (node-major)
  unsigned* Ab0    = (unsigned*)alloc((size_t)NN * 64 * 4); // packed bf16 layer-0 input
  unsigned* Bb     = (unsigned*)alloc((size_t)NN * 64 * 4); // packed bf16 H@W, slice-major [8][NN][8]
  int2*     ecw    = (int2*)alloc((size_t)EE * 8);
  float*    dinv   = (float*)alloc((size_t)NN * 4);
  int*      rowptr = (int*)alloc((size_t)(NN + 1) * 4);
  int*      bsum   = (int*)alloc((size_t)NSCB * 4);
  int*      gstart = (int*)alloc((size_t)(GG + 1) * 4);
  uint4*    Wf     = (uint4*)alloc((size_t)LL * 4096 * 16); // MFMA W fragments (hi/lo)
  float*    z1     = (float*)alloc((size_t)GG * FF * 4);
  float*    bnsc   = (float*)alloc((size_t)LL * 256 * 4);
  float*    idt    = (float*)alloc(256 * 4);
  float*    zsc    = (float*)alloc(256 * 4);
  (void)ws_size; (void)in_sizes; (void)n_in; (void)out_size;

  hipMemsetAsync(d_ws, 0, zero_bytes, stream);

  k_deg<<<(EE + 255) / 256, 256, 0, stream>>>(ei + EE, deg);
  k_dinv<<<(NN + 255) / 256, 256, 0, stream>>>(deg, dinv);
  k_bsum<<<NSCB, 256, 0, stream>>>(deg, bsum);
  k_rowptr<<<NSCB, 256, 0, stream>>>(deg, bsum, rowptr);
  k_fill<<<(EE + 255) / 256, 256, 0, stream>>>(ei, rowptr, cnt, dinv, ecw);
  k_bounds<<<(NN + 255) / 256, 256, 0, stream>>>(batch, gstart);
  k_cvt<<<(NN * 64 + 255) / 256, 256, 0, stream>>>(x, Ab0);
  k_id<<<1, 128, 0, stream>>>(idt);
  k_wcvt<<<64, 256, 0, stream>>>(Ws, Wf);

  for (int t = 0; t < LL; ++t) {
    const unsigned* Hb = (t == 0) ? Ab0 : Ar;
    const float* aff = (t == 0) ? idt : (bnsc + (size_t)(t - 1) * 256);
    k_mm<<<(NN + 63) / 64, 256, 0, stream>>>(Hb, aff, Wf + (size_t)t * 4096, Bb);
    k_agg<<<2048, 256, 0, stream>>>(Bb, rowptr, ecw, bs + t * FF, Ar, bnbuf + t * 256);
    k_bnfin<<<1, 128, 0, stream>>>(bnbuf + t * 256, gammas + t * FF, betas + t * FF,
                                   bnsc + (size_t)t * 256);
    k_gsum<<<GG * 8, 128, 0, stream>>>(Ar, gstart, praw + (size_t)t * GG * 128);
    k_pool<<<GG, 128, 0, stream>>>(praw + (size_t)t * GG * 128, bnsc + (size_t)t * 256,
                                   gstart, pooled + t * FF);
  }

  k_z1<<<GG, 128, 0, stream>>>(pooled, W1, b1, z1);
  k_zstat<<<1, 128, 0, stream>>>(z1, g1, bt1, zsc);
  k_out<<<GG, 128, 0, stream>>>(z1, zsc, W2, b2, out);
}

// Round 11
// 868.821 us; speedup vs baseline: 1.4594x; 1.4594x over previous
//
#include <hip/hip_runtime.h>

#define NN 100000
#define EE 1600000
#define FF 128
#define LL 4
#define GG 512
#define OUTC 10
#define EPSF 1e-5f
#define NSCB ((NN + 255) / 256)   // 391 scan blocks

typedef __attribute__((ext_vector_type(8))) short short8;
typedef __attribute__((ext_vector_type(4))) float f32x4;

__device__ inline unsigned bf16rne(float f) {
  unsigned u = __float_as_uint(f);
  return (u + 0x7fffu + ((u >> 16) & 1u)) >> 16;
}
__device__ inline unsigned packbf(float lo, float hi) {
  return bf16rne(lo) | (bf16rne(hi) << 16);
}
__device__ inline float bflo(unsigned u) { return __uint_as_float(u << 16); }
__device__ inline float bfhi(unsigned u) { return __uint_as_float(u & 0xffff0000u); }

// ---------- graph setup ----------

__global__ __launch_bounds__(256) void k_deg(const int* __restrict__ col, int* __restrict__ deg) {
  int e = blockIdx.x * 256 + threadIdx.x;
  if (e < EE) atomicAdd(&deg[col[e]], 1);
}

__global__ __launch_bounds__(256) void k_dinv(const int* __restrict__ deg, float* __restrict__ dinv) {
  int n = blockIdx.x * 256 + threadIdx.x;
  if (n < NN) {
    int d = deg[n];
    dinv[n] = d > 0 ? rsqrtf((float)d) : 0.0f;
  }
}

// per-block degree sums (391 blocks x 256)
__global__ __launch_bounds__(256) void k_bsum(const int* __restrict__ deg, int* __restrict__ bsum) {
  int i = blockIdx.x * 256 + threadIdx.x;
  int v = (i < NN) ? deg[i] : 0;
#pragma unroll
  for (int off = 32; off > 0; off >>= 1) v += __shfl_down(v, off, 64);
  __shared__ int ws[4];
  if ((threadIdx.x & 63) == 0) ws[threadIdx.x >> 6] = v;
  __syncthreads();
  if (threadIdx.x == 0) bsum[blockIdx.x] = ws[0] + ws[1] + ws[2] + ws[3];
}

// each block: scan all block sums in LDS (redundant), local scan of its 256 degs,
// write exclusive rowptr. rowptr[NN] = EE (constant).
__global__ __launch_bounds__(256) void k_rowptr(const int* __restrict__ deg,
                                                const int* __restrict__ bsum,
                                                int* __restrict__ rowptr) {
  __shared__ int sb[512];
  __shared__ int sd[256];
  const int t = threadIdx.x;
  sb[t]       = (t < NSCB) ? bsum[t] : 0;
  sb[t + 256] = (t + 256 < NSCB) ? bsum[t + 256] : 0;
  __syncthreads();
#pragma unroll
  for (int off = 1; off < 512; off <<= 1) {
    int v0 = (t >= off) ? sb[t - off] : 0;
    int v1 = sb[t + 256 - off];
    __syncthreads();
    sb[t] += v0;
    sb[t + 256] += v1;
    __syncthreads();
  }
  const int bpre = (blockIdx.x == 0) ? 0 : sb[blockIdx.x - 1];
  const int i = blockIdx.x * 256 + t;
  const int d = (i < NN) ? deg[i] : 0;
  sd[t] = d;
  __syncthreads();
#pragma unroll
  for (int off = 1; off < 256; off <<= 1) {
    int v = (t >= off) ? sd[t - off] : 0;
    __syncthreads();
    sd[t] += v;
    __syncthreads();
  }
  if (i < NN) rowptr[i] = bpre + sd[t] - d;
  if (blockIdx.x == 0 && t == 0) rowptr[NN] = EE;
}

// build CSR: one interleaved (src, weight) int2 store per edge
__global__ __launch_bounds__(256) void k_fill(const int* __restrict__ ei,
                                              const int* __restrict__ rowptr,
                                              int* __restrict__ cnt,
                                              const float* __restrict__ dinv,
                                              int2* __restrict__ ecw) {
  int e = blockIdx.x * 256 + threadIdx.x;
  if (e >= EE) return;
  int r = ei[e];
  int cl = ei[EE + e];
  int slot = rowptr[cl] + atomicAdd(&cnt[cl], 1);
  ecw[slot] = make_int2(r, __float_as_int(dinv[r] * dinv[cl]));
}

// batch is sorted: gstart[g] = first node of graph g; gstart[GG] = NN
__global__ __launch_bounds__(256) void k_bounds(const int* __restrict__ batch, int* __restrict__ gstart) {
  int n = blockIdx.x * 256 + threadIdx.x;
  if (n >= NN) return;
  int b = batch[n];
  if (n == 0) {
    for (int g = 0; g <= b; ++g) gstart[g] = 0;
  } else {
    int bp = batch[n - 1];
    for (int g = bp + 1; g <= b; ++g) gstart[g] = n;
  }
  if (n == NN - 1) {
    for (int g = b + 1; g <= GG; ++g) gstart[g] = NN;
  }
}

// ---------- bf16 conversions ----------

// x[N,128] fp32 -> Ab packed bf16 pairs
__global__ __launch_bounds__(256) void k_cvt(const float* __restrict__ x, unsigned* __restrict__ Ab) {
  int i = blockIdx.x * 256 + threadIdx.x;
  if (i < NN * 64) {
    float2 v = *(const float2*)(x + (size_t)i * 2);
    Ab[i] = packbf(v.x, v.y);
  }
}

// identity affine table for layer 0
__global__ __launch_bounds__(128) void k_id(float* __restrict__ idt) {
  idt[threadIdx.x] = 1.0f;
  idt[128 + threadIdx.x] = 0.0f;
}

// W[L,128,128] fp32 -> per-layer MFMA B-fragments, hi/lo bf16 split.
__global__ __launch_bounds__(256) void k_wcvt(const float* __restrict__ Ws, uint4* __restrict__ Wf) {
  int tid = blockIdx.x * 256 + threadIdx.x;   // 0..16383
  int t = tid >> 12;
  int r = tid & 4095;
  int lane = r & 63;
  int which = (r >> 6) & 1;
  int ct = (r >> 7) & 7;
  int kc = r >> 10;
  int n = ct * 16 + (lane & 15);
  int k0 = kc * 32 + (lane >> 4) * 8;
  const float* W = Ws + t * 16384;
  unsigned h[8];
#pragma unroll
  for (int j = 0; j < 8; ++j) {
    float w = W[(k0 + j) * 128 + n];
    unsigned hb = bf16rne(w);
    if (which == 0) {
      h[j] = hb;
    } else {
      float hf = __uint_as_float(hb << 16);
      h[j] = bf16rne(w - hf);
    }
  }
  uint4 o;
  o.x = h[0] | (h[1] << 16);
  o.y = h[2] | (h[3] << 16);
  o.z = h[4] | (h[5] << 16);
  o.w = h[6] | (h[7] << 16);
  Wf[tid] = o;
}

// ---------- per-layer GEMM via MFMA with fused input BN affine ----------
// Bb[N,128] (node-major packed bf16) = (aff_sc * Hb + aff_sh) @ (Whi+Wlo)
__global__ __launch_bounds__(256) void k_mm(const unsigned* __restrict__ Hb,
                                            const float* __restrict__ aff,   // [256] sc|sh
                                            const uint4* __restrict__ Wf,
                                            unsigned* __restrict__ Bb) {
  const int lane = threadIdx.x & 63;
  const int w = threadIdx.x >> 6;
  const int quad = lane >> 4;
  const int m = lane & 15;
  const int rowbase = blockIdx.x * 64 + w * 16;
  const int arow = min(rowbase + m, NN - 1);
  const uint4* A4 = (const uint4*)Hb;
  f32x4 acc[8];
#pragma unroll
  for (int ct = 0; ct < 8; ++ct) acc[ct] = (f32x4){0.f, 0.f, 0.f, 0.f};
#pragma unroll
  for (int kc = 0; kc < 4; ++kc) {
    uint4 av = A4[arow * 16 + kc * 4 + quad];
    const int cb = kc * 32 + quad * 8;
    float4 sc0 = *(const float4*)(aff + cb);
    float4 sc1 = *(const float4*)(aff + cb + 4);
    float4 sh0 = *(const float4*)(aff + 128 + cb);
    float4 sh1 = *(const float4*)(aff + 128 + cb + 4);
    uint4 hv;
    hv.x = packbf(fmaf(bflo(av.x), sc0.x, sh0.x), fmaf(bfhi(av.x), sc0.y, sh0.y));
    hv.y = packbf(fmaf(bflo(av.y), sc0.z, sh0.z), fmaf(bfhi(av.y), sc0.w, sh0.w));
    hv.z = packbf(fmaf(bflo(av.z), sc1.x, sh1.x), fmaf(bfhi(av.z), sc1.y, sh1.y));
    hv.w = packbf(fmaf(bflo(av.w), sc1.z, sh1.z), fmaf(bfhi(av.w), sc1.w, sh1.w));
    short8 af = *(short8*)&hv;
#pragma unroll
    for (int ct = 0; ct < 8; ++ct) {
      uint4 bh = Wf[((kc * 8 + ct) * 2 + 0) * 64 + lane];
      uint4 bl = Wf[((kc * 8 + ct) * 2 + 1) * 64 + lane];
      acc[ct] = __builtin_amdgcn_mfma_f32_16x16x32_bf16(af, *(short8*)&bh, acc[ct], 0, 0, 0);
      acc[ct] = __builtin_amdgcn_mfma_f32_16x16x32_bf16(af, *(short8*)&bl, acc[ct], 0, 0, 0);
    }
  }
#pragma unroll
  for (int ct = 0; ct < 8; ++ct) {
#pragma unroll
    for (int r = 0; r < 4; ++r) {
      float v = acc[ct][r];
      float vo = __shfl_xor(v, 1);
      int row = rowbase + quad * 4 + r;
      if ((lane & 1) == 0 && row < NN) {
        Bb[row * 64 + ct * 8 + (m >> 1)] = packbf(v, vo);
      }
    }
  }
}

// ---------- aggregation (round-6 structure, best measured: ~100 us) ----------
// lane = (edge-parity half h = lane>>5, channel-quad cl = lane&31). Each gather is a
// uint2 (4 channels) of one edge; a pair of edges per step across the two halves.
// 64-edge staged chunks; groups of 4 pairs (8 edges) double-buffered so the next
// group's 4 loads are in flight while the current is consumed. Stats and the packed
// store on the h=0 half after a shfl_xor(32) combine.
__global__ __launch_bounds__(256) void k_agg(const unsigned* __restrict__ Bb,
                                             const int* __restrict__ rowptr,
                                             const int2* __restrict__ ecw,
                                             const float* __restrict__ bias,
                                             unsigned* __restrict__ Ar,
                                             float* __restrict__ bnbuf) {
  const int lane = threadIdx.x & 63;
  const int wave = threadIdx.x >> 6;
  const int h = lane >> 5;
  const int cl = lane & 31;
  const int gwave = blockIdx.x * 4 + wave;
  const int nwaves = gridDim.x * 4;
  const uint2* B2 = (const uint2*)Bb;
  const float4 bv = *(const float4*)(bias + 4 * cl);
  float s0 = 0.f, s1 = 0.f, s2 = 0.f, s3 = 0.f;
  float q0 = 0.f, q1 = 0.f, q2 = 0.f, q3 = 0.f;
  for (int n = gwave; n < NN; n += nwaves) {
    const int beg = rowptr[n];
    const int end = rowptr[n + 1];
    float a0 = 0.f, a1 = 0.f, a2 = 0.f, a3 = 0.f;
    for (int base = beg; base < end; base += 64) {
      const int myj = base + lane;
      const int2 cur = (myj < end) ? ecw[myj] : make_int2(0, 0);
      uint2 u0[4], u1[4];
      // prologue: issue group 0 (edges base..base+7)
#pragma unroll
      for (int j = 0; j < 4; ++j) {
        int src = __shfl(cur.x, 2 * j + h);
        u0[j] = B2[(unsigned)src * 32 + (unsigned)cl];
      }
#pragma unroll
      for (int g = 0; g < 8; ++g) {
        if (base + (g + 1) * 8 < end) {   // wave-uniform: issue next group
#pragma unroll
          for (int j = 0; j < 4; ++j) {
            int src = __shfl(cur.x, 2 * ((g + 1) * 4 + j) + h);
            if (g & 1) u0[j] = B2[(unsigned)src * 32 + (unsigned)cl];
            else       u1[j] = B2[(unsigned)src * 32 + (unsigned)cl];
          }
        }
        if (base + g * 8 < end) {         // wave-uniform: consume current group
#pragma unroll
          for (int j = 0; j < 4; ++j) {
            float w = __shfl(__int_as_float(cur.y), 2 * (g * 4 + j) + h);
            uint2 u = (g & 1) ? u1[j] : u0[j];
            a0 = fmaf(w, bflo(u.x), a0);
            a1 = fmaf(w, bfhi(u.x), a1);
            a2 = fmaf(w, bflo(u.y), a2);
            a3 = fmaf(w, bfhi(u.y), a3);
          }
        }
      }
    }
    a0 += __shfl_xor(a0, 32);
    a1 += __shfl_xor(a1, 32);
    a2 += __shfl_xor(a2, 32);
    a3 += __shfl_xor(a3, 32);
    a0 = fmaxf(a0 + bv.x, 0.f);
    a1 = fmaxf(a1 + bv.y, 0.f);
    a2 = fmaxf(a2 + bv.z, 0.f);
    a3 = fmaxf(a3 + bv.w, 0.f);
    if (h == 0) {
      uint2 o;
      o.x = packbf(a0, a1);
      o.y = packbf(a2, a3);
      ((uint2*)Ar)[(size_t)n * 32 + cl] = o;
      s0 += a0; s1 += a1; s2 += a2; s3 += a3;
      q0 = fmaf(a0, a0, q0); q1 = fmaf(a1, a1, q1);
      q2 = fmaf(a2, a2, q2); q3 = fmaf(a3, a3, q3);
    }
  }
  __shared__ float sred[4][256];
  if (h == 0) {
    *(float4*)&sred[wave][4 * cl] = make_float4(s0, s1, s2, s3);
    *(float4*)&sred[wave][128 + 4 * cl] = make_float4(q0, q1, q2, q3);
  }
  __syncthreads();
  const int t = threadIdx.x;
  float tot = (sred[0][t] + sred[1][t]) + (sred[2][t] + sred[3][t]);
  atomicAdd(&bnbuf[t], tot);
}

__global__ __launch_bounds__(128) void k_bnfin(const float* __restrict__ bnbuf,
                                               const float* __restrict__ gamma,
                                               const float* __restrict__ beta,
                                               float* __restrict__ bnsc) {
  const int c = threadIdx.x;
  float mu = bnbuf[c] * (1.0f / NN);
  float var = bnbuf[128 + c] * (1.0f / NN) - mu * mu;
  float inv = rsqrtf(var + EPSF);
  float sc = gamma[c] * inv;
  bnsc[c] = sc;
  bnsc[128 + c] = beta[c] - mu * sc;
}

// per-graph raw pooled sums of relu output (sorted ranges, coarse atomics)
__global__ __launch_bounds__(128) void k_gsum(const unsigned* __restrict__ Ar,
                                              const int* __restrict__ gstart,
                                              float* __restrict__ praw) {
  const int g = blockIdx.x >> 3;
  const int sub = blockIdx.x & 7;
  const int st = gstart[g];
  const int en = gstart[g + 1];
  const int cnt = en - st;
  if (cnt <= 0) return;
  const int per = (cnt + 7) >> 3;
  const int ns = st + sub * per;
  const int ne = min(ns + per, en);
  if (ns >= ne) return;
  const int cp = threadIdx.x & 63;
  const int half = threadIdx.x >> 6;
  float accx = 0.f, accy = 0.f;
  for (int n = ns + half; n < ne; n += 2) {
    unsigned u = Ar[(size_t)n * 64 + cp];
    accx += bflo(u);
    accy += bfhi(u);
  }
  atomicAdd(&praw[(size_t)g * 128 + 2 * cp], accx);
  atomicAdd(&praw[(size_t)g * 128 + 2 * cp + 1], accy);
}

// pooled[g, t*128+c] = sc[c]*S_g[c] + sh[c]*cnt_g (linearized BN over per-graph sums)
__global__ __launch_bounds__(128) void k_pool(const float* __restrict__ praw,
                                              const float* __restrict__ bnsc,
                                              const int* __restrict__ gstart,
                                              float* __restrict__ pooledt) {
  const int g = blockIdx.x;
  const int c = threadIdx.x;
  const float cntf = (float)(gstart[g + 1] - gstart[g]);
  pooledt[(size_t)g * 512 + c] = fmaf(bnsc[c], praw[(size_t)g * 128 + c], bnsc[128 + c] * cntf);
}

// ---------- head ----------

__global__ __launch_bounds__(128) void k_z1(const float* __restrict__ pooled,
                                            const float* __restrict__ W1,
                                            const float* __restrict__ b1,
                                            float* __restrict__ z1) {
  __shared__ float sp[512];
  const int g = blockIdx.x;
  for (int i = threadIdx.x; i < 512; i += 128) sp[i] = pooled[(size_t)g * 512 + i];
  __syncthreads();
  const int c = threadIdx.x;
  float acc = b1[c];
  for (int j = 0; j < 512; ++j) acc = fmaf(sp[j], W1[j * 128 + c], acc);
  z1[(size_t)g * 128 + c] = acc;
}

__global__ __launch_bounds__(128) void k_zstat(const float* __restrict__ z1,
                                               const float* __restrict__ g1,
                                               const float* __restrict__ bt1,
                                               float* __restrict__ zsc) {
  const int c = threadIdx.x;
  float s = 0.f, q = 0.f;
  for (int g = 0; g < GG; ++g) {
    float v = z1[g * 128 + c];
    s += v;
    q = fmaf(v, v, q);
  }
  float mu = s * (1.0f / GG);
  float var = q * (1.0f / GG) - mu * mu;
  float inv = rsqrtf(var + EPSF);
  float sc = g1[c] * inv;
  zsc[c] = sc;
  zsc[128 + c] = bt1[c] - mu * sc;
}

__global__ __launch_bounds__(128) void k_out(const float* __restrict__ z1,
                                             const float* __restrict__ zsc,
                                             const float* __restrict__ W2,
                                             const float* __restrict__ b2,
                                             float* __restrict__ out) {
  __shared__ float zr[128];
  const int g = blockIdx.x;
  const int c = threadIdx.x;
  zr[c] = fmaxf(fmaf(z1[(size_t)g * 128 + c], zsc[c], zsc[128 + c]), 0.f);
  __syncthreads();
  if (c < OUTC) {
    float acc = b2[c];
    for (int k = 0; k < 128; ++k) acc = fmaf(zr[k], W2[k * OUTC + c], acc);
    out[(size_t)g * OUTC + c] = acc;
  }
}

// ---------- launch ----------

extern "C" void kernel_launch(void* const* d_in, const int* in_sizes, int n_in,
                              void* d_out, int out_size, void* d_ws, size_t ws_size,
                              hipStream_t stream) {
  const float* x      = (const float*)d_in[0];
  const int*   ei     = (const int*)d_in[1];
  const int*   batch  = (const int*)d_in[2];
  const float* Ws     = (const float*)d_in[3];
  const float* bs     = (const float*)d_in[4];
  const float* gammas = (const float*)d_in[5];
  const float* betas  = (const float*)d_in[6];
  const float* W1     = (const float*)d_in[7];
  const float* b1     = (const float*)d_in[8];
  const float* g1     = (const float*)d_in[9];
  const float* bt1    = (const float*)d_in[10];
  const float* W2     = (const float*)d_in[11];
  const float* b2     = (const float*)d_in[12];
  float* out = (float*)d_out;

  char* ws = (char*)d_ws;
  size_t off = 0;
  auto alloc = [&](size_t bytes) -> void* {
    void* p = ws + off;
    off = (off + bytes + 255) & ~(size_t)255;
    return p;
  };
  // zero-initialized region (single memset)
  int*   deg    = (int*)alloc((size_t)NN * 4);
  int*   cnt    = (int*)alloc((size_t)NN * 4);
  float* bnbuf  = (float*)alloc((size_t)LL * 256 * 4);
  float* praw   = (float*)alloc((size_t)LL * GG * 128 * 4);
  size_t zero_bytes = off;
  // rest
  float* pooled    = (float*)alloc((size_t)GG * 512 * 4);
  unsigned* Ar     = (unsigned*)alloc((size_t)NN * 64 * 4); // packed bf16 relu output (node-major)
  unsigned* Ab0    = (unsigned*)alloc((size_t)NN * 64 * 4); // packed bf16 layer-0 input
  unsigned* Bb     = (unsigned*)alloc((size_t)NN * 64 * 4); // packed bf16 H@W (node-major gather src)
  int2*     ecw    = (int2*)alloc((size_t)EE * 8);
  float*    dinv   = (float*)alloc((size_t)NN * 4);
  int*      rowptr = (int*)alloc((size_t)(NN + 1) * 4);
  int*      bsum   = (int*)alloc((size_t)NSCB * 4);
  int*      gstart = (int*)alloc((size_t)(GG + 1) * 4);
  uint4*    Wf     = (uint4*)alloc((size_t)LL * 4096 * 16); // MFMA W fragments (hi/lo)
  float*    z1     = (float*)alloc((size_t)GG * FF * 4);
  float*    bnsc   = (float*)alloc((size_t)LL * 256 * 4);
  float*    idt    = (float*)alloc(256 * 4);
  float*    zsc    = (float*)alloc(256 * 4);
  (void)ws_size; (void)in_sizes; (void)n_in; (void)out_size;

  hipMemsetAsync(d_ws, 0, zero_bytes, stream);

  k_deg<<<(EE + 255) / 256, 256, 0, stream>>>(ei + EE, deg);
  k_dinv<<<(NN + 255) / 256, 256, 0, stream>>>(deg, dinv);
  k_bsum<<<NSCB, 256, 0, stream>>>(deg, bsum);
  k_rowptr<<<NSCB, 256, 0, stream>>>(deg, bsum, rowptr);
  k_fill<<<(EE + 255) / 256, 256, 0, stream>>>(ei, rowptr, cnt, dinv, ecw);
  k_bounds<<<(NN + 255) / 256, 256, 0, stream>>>(batch, gstart);
  k_cvt<<<(NN * 64 + 255) / 256, 256, 0, stream>>>(x, Ab0);
  k_id<<<1, 128, 0, stream>>>(idt);
  k_wcvt<<<64, 256, 0, stream>>>(Ws, Wf);

  for (int t = 0; t < LL; ++t) {
    const unsigned* Hb = (t == 0) ? Ab0 : Ar;
    const float* aff = (t == 0) ? idt : (bnsc + (size_t)(t - 1) * 256);
    k_mm<<<(NN + 63) / 64, 256, 0, stream>>>(Hb, aff, Wf + (size_t)t * 4096, Bb);
    k_agg<<<2048, 256, 0, stream>>>(Bb, rowptr, ecw, bs + t * FF, Ar, bnbuf + t * 256);
    k_bnfin<<<1, 128, 0, stream>>>(bnbuf + t * 256, gammas + t * FF, betas + t * FF,
                                   bnsc + (size_t)t * 256);
    k_gsum<<<GG * 8, 128, 0, stream>>>(Ar, gstart, praw + (size_t)t * GG * 128);
    k_pool<<<GG, 128, 0, stream>>>(praw + (size_t)t * GG * 128, bnsc + (size_t)t * 256,
                                   gstart, pooled + t * FF);
  }

  k_z1<<<GG, 128, 0, stream>>>(pooled, W1, b1, z1);
  k_zstat<<<1, 128, 0, stream>>>(z1, g1, bt1, zsc);
  k_out<<<GG, 128, 0, stream>>>(z1, zsc, W2, b2, out);
}